// Round 5
// baseline (133.931 us; speedup 1.0000x reference)
//
#include <hip/hip_runtime.h>
#include <math.h>

// Problem constants (SCDM_89318139888190)
#define Bdim 8
#define Fdim 256
#define Tdim 32
#define Ddim 1024
#define NEGV (-1e30f)
#define TANH_SCALE 2.8853900817779268f   // 2*log2(e): tanh(x)=1-2*rcp(exp2(c*x)+1)
#define LOG2E 1.4426950408889634f

typedef unsigned short ushort;
using short8  = __attribute__((ext_vector_type(8))) short;   // 8 bf16 in 4 VGPRs
using floatx4 = __attribute__((ext_vector_type(4))) float;   // MFMA accumulator

__device__ __forceinline__ float fexp2(float x) { return __builtin_amdgcn_exp2f(x); }
__device__ __forceinline__ float frcp(float x)  { return __builtin_amdgcn_rcpf(x); }

__device__ __forceinline__ float fast_tanh(float x) {
    return 1.0f - 2.0f * frcp(fexp2(x * TANH_SCALE) + 1.0f);
}

__device__ __forceinline__ ushort f2bf(float f) {
    unsigned u = __float_as_uint(f);
    unsigned r = u + 0x7FFFu + ((u >> 16) & 1u);
    return (ushort)(r >> 16);
}

// async global->LDS, 16B per lane; LDS dst = base + lane*16 (wave-uniform base)
#define GLOAD_LDS16(gp, lp) __builtin_amdgcn_global_load_lds(                   \
    (const __attribute__((address_space(1))) void*)(gp),                        \
    (__attribute__((address_space(3))) void*)(lp), 16, 0, 0)

// ---------------------------------------------------------------------------
// prep (merged): blocks [0,2304) cast feat/txt rows to bf16;
// blocks [2304, 2304+2048) transpose+cast W / Ws 32x32 tiles.
// ---------------------------------------------------------------------------
__global__ __launch_bounds__(256) void prep(
    const float* __restrict__ feat, const float* __restrict__ txt,
    const float* __restrict__ W, const float* __restrict__ Ws,
    ushort* __restrict__ featB, ushort* __restrict__ txtB,
    ushort* __restrict__ WtB, ushort* __restrict__ WstB)
{
    __shared__ ushort tile[32][33];
    const int blk = blockIdx.x;
    const int NCAST = Bdim * Fdim + Bdim * Tdim;   // 2304
    if (blk < NCAST) {
        const float* in; ushort* out; int base;
        if (blk < Bdim * Fdim) { in = feat; out = featB; base = blk * Ddim; }
        else { in = txt; out = txtB; base = (blk - Bdim * Fdim) * Ddim; }
        const int i = base + threadIdx.x * 4;
        float4 v = *(const float4*)(in + i);
        ushort4 o;
        o.x = f2bf(v.x); o.y = f2bf(v.y); o.z = f2bf(v.z); o.w = f2bf(v.w);
        *(ushort4*)(out + i) = o;
    } else {
        int t = blk - NCAST;                      // 0..2047
        const float* in = (t < 1024) ? W : Ws;
        ushort* out = (t < 1024) ? WtB : WstB;
        t &= 1023;
        const int bx = (t & 31) * 32;             // col (n) base
        const int by = (t >> 5) * 32;             // row (k) base
        const int tx = threadIdx.x & 31;
        const int tg = threadIdx.x >> 5;
        #pragma unroll
        for (int r = tg; r < 32; r += 8)
            tile[r][tx] = f2bf(in[(size_t)(by + r) * Ddim + bx + tx]);
        __syncthreads();
        #pragma unroll
        for (int r = tg; r < 32; r += 8)
            out[(size_t)(bx + r) * Ddim + by + tx] = tile[tx][r];
    }
}

// ---------------------------------------------------------------------------
// bf16 MFMA GEMM, m97-style staging: BM=128, BN=64, BK=32, 256 threads.
// global_load_lds width=16 staging; wave computes 64x32 (4x2 of 16x16x32).
// blockIdx.y 0..15 -> feat_proj; 16..17 -> txt_proj (+bias).
// Epilogue scales by TANH_SCALE (outputs feed the tanh argument in attn).
// ---------------------------------------------------------------------------
#define GBM 128
#define GBN 64
#define GBK 32

__global__ __launch_bounds__(256) void gemm_dual(
    const ushort* __restrict__ A1, const ushort* __restrict__ Bt1, float* __restrict__ C1,
    const ushort* __restrict__ A2, const ushort* __restrict__ Bt2, float* __restrict__ C2,
    const float* __restrict__ bias2)
{
    const int K = Ddim, N = Ddim;
    const int by = blockIdx.y;
    const ushort* A; const ushort* Bt; float* C; const float* bias; int m0;
    if (by < 16) { A = A1; Bt = Bt1; C = C1; bias = nullptr; m0 = by * GBM; }
    else         { A = A2; Bt = Bt2; C = C2; bias = bias2;  m0 = (by - 16) * GBM; }
    const int n0 = blockIdx.x * GBN;

    __shared__ __align__(16) ushort As[GBM * GBK];   // 8 KB
    __shared__ __align__(16) ushort Bs[GBN * GBK];   // 4 KB

    const int tid  = threadIdx.x;
    const int l    = tid & 63;
    const int wave = tid >> 6;

    const int crow = l >> 2;
    const int ccol = (l & 3) * 8;

    const int wm = (wave >> 1) * 64;
    const int wn = (wave & 1) * 32;

    floatx4 acc[4][2];
    #pragma unroll
    for (int i = 0; i < 4; ++i)
        #pragma unroll
        for (int j = 0; j < 2; ++j)
            acc[i][j] = (floatx4){0.0f, 0.0f, 0.0f, 0.0f};

    const int lm = l & 15;
    const int lk = (l >> 4) * 8;

    const ushort* aSrc0 = A  + (size_t)(m0 + wave * 16       + crow) * K + ccol;
    const ushort* aSrc1 = A  + (size_t)(m0 + (wave + 4) * 16 + crow) * K + ccol;
    const ushort* bSrc  = Bt + (size_t)(n0 + wave * 16       + crow) * K + ccol;
    ushort* aDst0 = &As[(wave * 16) * GBK];
    ushort* aDst1 = &As[((wave + 4) * 16) * GBK];
    ushort* bDst  = &Bs[(wave * 16) * GBK];

    for (int k0 = 0; k0 < K; k0 += GBK) {
        __syncthreads();
        GLOAD_LDS16(aSrc0 + k0, aDst0);
        GLOAD_LDS16(aSrc1 + k0, aDst1);
        GLOAD_LDS16(bSrc  + k0, bDst);
        __syncthreads();

        short8 af0 = *(const short8*)&As[(wm +  0 + lm) * GBK + lk];
        short8 af1 = *(const short8*)&As[(wm + 16 + lm) * GBK + lk];
        short8 af2 = *(const short8*)&As[(wm + 32 + lm) * GBK + lk];
        short8 af3 = *(const short8*)&As[(wm + 48 + lm) * GBK + lk];
        short8 bf0 = *(const short8*)&Bs[(wn +  0 + lm) * GBK + lk];
        short8 bf1 = *(const short8*)&Bs[(wn + 16 + lm) * GBK + lk];
        acc[0][0] = __builtin_amdgcn_mfma_f32_16x16x32_bf16(af0, bf0, acc[0][0], 0, 0, 0);
        acc[0][1] = __builtin_amdgcn_mfma_f32_16x16x32_bf16(af0, bf1, acc[0][1], 0, 0, 0);
        acc[1][0] = __builtin_amdgcn_mfma_f32_16x16x32_bf16(af1, bf0, acc[1][0], 0, 0, 0);
        acc[1][1] = __builtin_amdgcn_mfma_f32_16x16x32_bf16(af1, bf1, acc[1][1], 0, 0, 0);
        acc[2][0] = __builtin_amdgcn_mfma_f32_16x16x32_bf16(af2, bf0, acc[2][0], 0, 0, 0);
        acc[2][1] = __builtin_amdgcn_mfma_f32_16x16x32_bf16(af2, bf1, acc[2][1], 0, 0, 0);
        acc[3][0] = __builtin_amdgcn_mfma_f32_16x16x32_bf16(af3, bf0, acc[3][0], 0, 0, 0);
        acc[3][1] = __builtin_amdgcn_mfma_f32_16x16x32_bf16(af3, bf1, acc[3][1], 0, 0, 0);
    }

    const int rowq = (l >> 4) * 4;
    #pragma unroll
    for (int im = 0; im < 4; ++im) {
        #pragma unroll
        for (int in_ = 0; in_ < 2; ++in_) {
            const int col = n0 + wn + in_ * 16 + lm;
            float badd = (bias != nullptr) ? bias[col] : 0.0f;
            #pragma unroll
            for (int r = 0; r < 4; ++r) {
                const int row = m0 + wm + im * 16 + rowq + r;
                C[(size_t)row * N + col] = (acc[im][in_][r] + badd) * TANH_SCALE;
            }
        }
    }
}

// ---------------------------------------------------------------------------
// attn v3: one block per 4 f-rows (NF=4). fp/w fragments in registers,
// tanh = 1-2*rcp(exp2(arg)+1) with arg pre-scaled in the GEMM epilogue.
// rho = sumw - 2*sum(w*r). Softmax over 2 waves (2 f-rows each).
// launch_bounds(256,2): VGPR headroom for compiler load pipelining; grid 512
// = 2 blocks/CU anyway.
// ---------------------------------------------------------------------------
__global__ __launch_bounds__(256, 2) void attn_fused(
    const float* __restrict__ feat,   // [B,F,D] raw
    const float* __restrict__ txt,    // [B,T,D] raw
    const int*   __restrict__ qmask,  // [B,T]
    const float* __restrict__ fp_s,   // [B*F,D]  feat_proj * c
    const float* __restrict__ tp_s,   // [B*T,D]  (txt_proj+b) * c
    const float* __restrict__ wvec,   // [D]
    const float* __restrict__ Wcw,    // [D]
    const float* __restrict__ bcw,    // [1]
    const float* __restrict__ Wcb,    // [D]
    const float* __restrict__ bcb,    // [1]
    float* __restrict__ out)          // [B,F,D]
{
    const int blk  = blockIdx.x;          // 0..511
    const int f0   = blk * 4;
    const int b    = f0 >> 8;
    const int tid  = threadIdx.x;
    const int lane = tid & 63;
    const int wave = tid >> 6;

    __shared__ float srho[4][Tdim];
    __shared__ float satt[4][Tdim];
    __shared__ float sred[4][8];

    // per-lane d-slice: d(it) = lane*4 + it*256; fp rows for 4 f's in regs
    float4 wv[4], fv[4][4];               // fv[ff][it]
    const float* fr = fp_s + (size_t)f0 * Ddim;
    #pragma unroll
    for (int it = 0; it < 4; ++it) {
        const int d = lane * 4 + it * 256;
        wv[it] = *(const float4*)&wvec[d];
        #pragma unroll
        for (int ff = 0; ff < 4; ++ff)
            fv[ff][it] = *(const float4*)&fr[(size_t)ff * Ddim + d];
    }
    float sumw = 0.0f;
    #pragma unroll
    for (int it = 0; it < 4; ++it)
        sumw += wv[it].x + wv[it].y + wv[it].z + wv[it].w;
    #pragma unroll
    for (int off = 32; off; off >>= 1) sumw += __shfl_xor(sumw, off, 64);

    // ---- phase 1: logits. wave handles t = wave*8 + tt; 4 f-chains ----
    const float* tpb = tp_s + (size_t)b * Tdim * Ddim;
    for (int tt = 0; tt < 8; ++tt) {
        const int t = wave * 8 + tt;
        const float* tr = tpb + (size_t)t * Ddim;
        float s[4] = {0.0f, 0.0f, 0.0f, 0.0f};
        #pragma unroll
        for (int it = 0; it < 4; ++it) {
            const int d = lane * 4 + it * 256;
            float4 tv = *(const float4*)&tr[d];
            #pragma unroll
            for (int ff = 0; ff < 4; ++ff) {
                float e, r;
                e = fexp2(tv.x + fv[ff][it].x); r = frcp(e + 1.0f); s[ff] = fmaf(wv[it].x, r, s[ff]);
                e = fexp2(tv.y + fv[ff][it].y); r = frcp(e + 1.0f); s[ff] = fmaf(wv[it].y, r, s[ff]);
                e = fexp2(tv.z + fv[ff][it].z); r = frcp(e + 1.0f); s[ff] = fmaf(wv[it].z, r, s[ff]);
                e = fexp2(tv.w + fv[ff][it].w); r = frcp(e + 1.0f); s[ff] = fmaf(wv[it].w, r, s[ff]);
            }
        }
        #pragma unroll
        for (int off = 32; off; off >>= 1) {
            s[0] += __shfl_xor(s[0], off, 64);
            s[1] += __shfl_xor(s[1], off, 64);
            s[2] += __shfl_xor(s[2], off, 64);
            s[3] += __shfl_xor(s[3], off, 64);
        }
        if (lane == 0) {
            srho[0][t] = s[0]; srho[1][t] = s[1];
            srho[2][t] = s[2]; srho[3][t] = s[3];
        }
    }
    __syncthreads();

    // ---- softmax: waves 0-1, each 32 lanes per f-row ----
    if (wave < 2) {
        const int f = wave * 2 + (lane >> 5), t = lane & 31;
        const float q = (float)qmask[b * Tdim + t];
        float L = sumw - 2.0f * srho[f][t] + (1.0f - q) * NEGV;
        float m = L;
        #pragma unroll
        for (int off = 16; off; off >>= 1) m = fmaxf(m, __shfl_xor(m, off, 64));
        float e = fexp2((L - m) * LOG2E);
        float ssum = e;
        #pragma unroll
        for (int off = 16; off; off >>= 1) ssum += __shfl_xor(ssum, off, 64);
        satt[f][t] = e * frcp(ssum);
    }
    __syncthreads();

    // ---- phase 2: txt_h for 4 f rows; thread owns d0 = tid*4 ----
    const float* txtb = txt + (size_t)b * Tdim * Ddim;
    const int d0 = tid * 4;
    float4 th[4] = {{0,0,0,0}, {0,0,0,0}, {0,0,0,0}, {0,0,0,0}};
    #pragma unroll 8
    for (int t = 0; t < Tdim; ++t) {
        float4 tv = *(const float4*)&txtb[(size_t)t * Ddim + d0];
        #pragma unroll
        for (int ff = 0; ff < 4; ++ff) {
            const float a = satt[ff][t];
            th[ff].x = fmaf(a, tv.x, th[ff].x);
            th[ff].y = fmaf(a, tv.y, th[ff].y);
            th[ff].z = fmaf(a, tv.z, th[ff].z);
            th[ff].w = fmaf(a, tv.w, th[ff].w);
        }
    }

    float4 wcw = *(const float4*)&Wcw[d0];
    float4 wcb = *(const float4*)&Wcb[d0];
    float p[8];
    #pragma unroll
    for (int ff = 0; ff < 4; ++ff) {
        p[ff * 2 + 0] = th[ff].x*wcw.x + th[ff].y*wcw.y + th[ff].z*wcw.z + th[ff].w*wcw.w;
        p[ff * 2 + 1] = th[ff].x*wcb.x + th[ff].y*wcb.y + th[ff].z*wcb.z + th[ff].w*wcb.w;
    }
    #pragma unroll
    for (int off = 32; off; off >>= 1)
        #pragma unroll
        for (int i = 0; i < 8; ++i)
            p[i] += __shfl_xor(p[i], off, 64);
    if (lane == 0)
        #pragma unroll
        for (int i = 0; i < 8; ++i) sred[wave][i] = p[i];
    __syncthreads();

    const float bcw0 = bcw[0], bcb0 = bcb[0];
    const float* ft = feat + (size_t)f0 * Ddim;
    #pragma unroll
    for (int ff = 0; ff < 4; ++ff) {
        const float cw = sred[0][ff*2] + sred[1][ff*2] + sred[2][ff*2] + sred[3][ff*2];
        const float cb = sred[0][ff*2+1] + sred[1][ff*2+1] + sred[2][ff*2+1] + sred[3][ff*2+1];
        const float w_s = fast_tanh(cw + bcw0);
        const float b_s = fast_tanh(cb + bcb0);
        float4 v = *(const float4*)&ft[(size_t)ff * Ddim + d0];
        float4 o;
        o.x = fmaf(w_s, v.x, b_s); o.y = fmaf(w_s, v.y, b_s);
        o.z = fmaf(w_s, v.z, b_s); o.w = fmaf(w_s, v.w, b_s);
        *(float4*)&out[(size_t)(f0 + ff) * Ddim + d0] = o;
    }
}

// ---------------------------------------------------------------------------
extern "C" void kernel_launch(void* const* d_in, const int* in_sizes, int n_in,
                              void* d_out, int out_size, void* d_ws, size_t ws_size,
                              hipStream_t stream) {
    const float* features = (const float*)d_in[0];   // [B,F,D]
    const float* textual  = (const float*)d_in[2];   // [B,T,D]
    const int*   q_masks  = (const int*)d_in[3];     // [B,T]
    const float* Ws       = (const float*)d_in[4];   // [D,D]
    const float* W        = (const float*)d_in[5];   // [D,D]
    const float* wvec     = (const float*)d_in[6];   // [D,1]
    const float* bvec     = (const float*)d_in[7];   // [1,D]
    const float* Wcw      = (const float*)d_in[8];   // [1,D]
    const float* bcw      = (const float*)d_in[9];   // [1]
    const float* Wcb      = (const float*)d_in[10];  // [1,D]
    const float* bcb      = (const float*)d_in[11];  // [1]
    float* out = (float*)d_out;

    float*  fp_ws = (float*)d_ws;                          // 2048*1024 f32 (scaled)
    float*  tp_ws = fp_ws + (size_t)Bdim * Fdim * Ddim;    // 256*1024 f32 (scaled)
    ushort* featB = (ushort*)(tp_ws + (size_t)Bdim * Tdim * Ddim);
    ushort* txtB  = featB + (size_t)Bdim * Fdim * Ddim;
    ushort* WtB   = txtB + (size_t)Bdim * Tdim * Ddim;
    ushort* WstB  = WtB + (size_t)Ddim * Ddim;

    // 1. merged prep: cast activations + transpose/cast weights
    prep<<<Bdim * Fdim + Bdim * Tdim + 2048, 256, 0, stream>>>(
        features, textual, W, Ws, featB, txtB, WtB, WstB);
    // 2. both projections, one MFMA dispatch (m97-style staging)
    gemm_dual<<<dim3(Ddim / GBN, 18), 256, 0, stream>>>(
        featB, WtB, fp_ws, txtB, WstB, tp_ws, bvec);
    // 3. fused attention + conditioning (4 f-rows per block)
    attn_fused<<<(Bdim * Fdim) / 4, 256, 0, stream>>>(
        features, textual, q_masks, fp_ws, tp_ws,
        wvec, Wcw, bcw, Wcb, bcb, out);
}

// Round 6
// 131.537 us; speedup vs baseline: 1.0182x; 1.0182x over previous
//
#include <hip/hip_runtime.h>
#include <math.h>

// Problem constants (SCDM_89318139888190)
#define Bdim 8
#define Fdim 256
#define Tdim 32
#define Ddim 1024
#define NEGV (-1e30f)
#define TANH_SCALE 2.8853900817779268f   // 2*log2(e): tanh(x)=1-2*rcp(exp2(c*x)+1)
#define LOG2E 1.4426950408889634f

typedef unsigned short ushort;
using short8  = __attribute__((ext_vector_type(8))) short;   // 8 bf16 in 4 VGPRs
using floatx4 = __attribute__((ext_vector_type(4))) float;   // MFMA accumulator

__device__ __forceinline__ float fexp2(float x) { return __builtin_amdgcn_exp2f(x); }
__device__ __forceinline__ float frcp(float x)  { return __builtin_amdgcn_rcpf(x); }

__device__ __forceinline__ float fast_tanh(float x) {
    return 1.0f - 2.0f * frcp(fexp2(x * TANH_SCALE) + 1.0f);
}

__device__ __forceinline__ ushort f2bf(float f) {
    unsigned u = __float_as_uint(f);
    unsigned r = u + 0x7FFFu + ((u >> 16) & 1u);
    return (ushort)(r >> 16);
}

// async global->LDS, 16B per lane; LDS dst = base + lane*16 (wave-uniform base)
#define GLOAD_LDS16(gp, lp) __builtin_amdgcn_global_load_lds(                   \
    (const __attribute__((address_space(1))) void*)(gp),                        \
    (__attribute__((address_space(3))) void*)(lp), 16, 0, 0)

// ---------------------------------------------------------------------------
// prep (merged): blocks [0,2304) cast feat/txt rows to bf16;
// blocks [2304, 2304+2048) transpose+cast W / Ws 32x32 tiles.
// ---------------------------------------------------------------------------
__global__ __launch_bounds__(256) void prep(
    const float* __restrict__ feat, const float* __restrict__ txt,
    const float* __restrict__ W, const float* __restrict__ Ws,
    ushort* __restrict__ featB, ushort* __restrict__ txtB,
    ushort* __restrict__ WtB, ushort* __restrict__ WstB)
{
    __shared__ ushort tile[32][33];
    const int blk = blockIdx.x;
    const int NCAST = Bdim * Fdim + Bdim * Tdim;   // 2304
    if (blk < NCAST) {
        const float* in; ushort* out; int base;
        if (blk < Bdim * Fdim) { in = feat; out = featB; base = blk * Ddim; }
        else { in = txt; out = txtB; base = (blk - Bdim * Fdim) * Ddim; }
        const int i = base + threadIdx.x * 4;
        float4 v = *(const float4*)(in + i);
        ushort4 o;
        o.x = f2bf(v.x); o.y = f2bf(v.y); o.z = f2bf(v.z); o.w = f2bf(v.w);
        *(ushort4*)(out + i) = o;
    } else {
        int t = blk - NCAST;                      // 0..2047
        const float* in = (t < 1024) ? W : Ws;
        ushort* out = (t < 1024) ? WtB : WstB;
        t &= 1023;
        const int bx = (t & 31) * 32;             // col (n) base
        const int by = (t >> 5) * 32;             // row (k) base
        const int tx = threadIdx.x & 31;
        const int tg = threadIdx.x >> 5;
        #pragma unroll
        for (int r = tg; r < 32; r += 8)
            tile[r][tx] = f2bf(in[(size_t)(by + r) * Ddim + bx + tx]);
        __syncthreads();
        #pragma unroll
        for (int r = tg; r < 32; r += 8)
            out[(size_t)(bx + r) * Ddim + by + tx] = tile[tx][r];
    }
}

// ---------------------------------------------------------------------------
// bf16 MFMA GEMM, m97-style staging: BM=128, BN=64, BK=32, 256 threads.
// global_load_lds width=16 staging; wave computes 64x32 (4x2 of 16x16x32).
// blockIdx.y 0..15 -> feat_proj; 16..17 -> txt_proj (+bias).
// Epilogue scales by TANH_SCALE (outputs feed the tanh argument in attn).
// ---------------------------------------------------------------------------
#define GBM 128
#define GBN 64
#define GBK 32

__global__ __launch_bounds__(256) void gemm_dual(
    const ushort* __restrict__ A1, const ushort* __restrict__ Bt1, float* __restrict__ C1,
    const ushort* __restrict__ A2, const ushort* __restrict__ Bt2, float* __restrict__ C2,
    const float* __restrict__ bias2)
{
    const int K = Ddim, N = Ddim;
    const int by = blockIdx.y;
    const ushort* A; const ushort* Bt; float* C; const float* bias; int m0;
    if (by < 16) { A = A1; Bt = Bt1; C = C1; bias = nullptr; m0 = by * GBM; }
    else         { A = A2; Bt = Bt2; C = C2; bias = bias2;  m0 = (by - 16) * GBM; }
    const int n0 = blockIdx.x * GBN;

    __shared__ __align__(16) ushort As[GBM * GBK];   // 8 KB
    __shared__ __align__(16) ushort Bs[GBN * GBK];   // 4 KB

    const int tid  = threadIdx.x;
    const int l    = tid & 63;
    const int wave = tid >> 6;

    const int crow = l >> 2;
    const int ccol = (l & 3) * 8;

    const int wm = (wave >> 1) * 64;
    const int wn = (wave & 1) * 32;

    floatx4 acc[4][2];
    #pragma unroll
    for (int i = 0; i < 4; ++i)
        #pragma unroll
        for (int j = 0; j < 2; ++j)
            acc[i][j] = (floatx4){0.0f, 0.0f, 0.0f, 0.0f};

    const int lm = l & 15;
    const int lk = (l >> 4) * 8;

    const ushort* aSrc0 = A  + (size_t)(m0 + wave * 16       + crow) * K + ccol;
    const ushort* aSrc1 = A  + (size_t)(m0 + (wave + 4) * 16 + crow) * K + ccol;
    const ushort* bSrc  = Bt + (size_t)(n0 + wave * 16       + crow) * K + ccol;
    ushort* aDst0 = &As[(wave * 16) * GBK];
    ushort* aDst1 = &As[((wave + 4) * 16) * GBK];
    ushort* bDst  = &Bs[(wave * 16) * GBK];

    for (int k0 = 0; k0 < K; k0 += GBK) {
        __syncthreads();
        GLOAD_LDS16(aSrc0 + k0, aDst0);
        GLOAD_LDS16(aSrc1 + k0, aDst1);
        GLOAD_LDS16(bSrc  + k0, bDst);
        __syncthreads();

        short8 af0 = *(const short8*)&As[(wm +  0 + lm) * GBK + lk];
        short8 af1 = *(const short8*)&As[(wm + 16 + lm) * GBK + lk];
        short8 af2 = *(const short8*)&As[(wm + 32 + lm) * GBK + lk];
        short8 af3 = *(const short8*)&As[(wm + 48 + lm) * GBK + lk];
        short8 bf0 = *(const short8*)&Bs[(wn +  0 + lm) * GBK + lk];
        short8 bf1 = *(const short8*)&Bs[(wn + 16 + lm) * GBK + lk];
        acc[0][0] = __builtin_amdgcn_mfma_f32_16x16x32_bf16(af0, bf0, acc[0][0], 0, 0, 0);
        acc[0][1] = __builtin_amdgcn_mfma_f32_16x16x32_bf16(af0, bf1, acc[0][1], 0, 0, 0);
        acc[1][0] = __builtin_amdgcn_mfma_f32_16x16x32_bf16(af1, bf0, acc[1][0], 0, 0, 0);
        acc[1][1] = __builtin_amdgcn_mfma_f32_16x16x32_bf16(af1, bf1, acc[1][1], 0, 0, 0);
        acc[2][0] = __builtin_amdgcn_mfma_f32_16x16x32_bf16(af2, bf0, acc[2][0], 0, 0, 0);
        acc[2][1] = __builtin_amdgcn_mfma_f32_16x16x32_bf16(af2, bf1, acc[2][1], 0, 0, 0);
        acc[3][0] = __builtin_amdgcn_mfma_f32_16x16x32_bf16(af3, bf0, acc[3][0], 0, 0, 0);
        acc[3][1] = __builtin_amdgcn_mfma_f32_16x16x32_bf16(af3, bf1, acc[3][1], 0, 0, 0);
    }

    const int rowq = (l >> 4) * 4;
    #pragma unroll
    for (int im = 0; im < 4; ++im) {
        #pragma unroll
        for (int in_ = 0; in_ < 2; ++in_) {
            const int col = n0 + wn + in_ * 16 + lm;
            float badd = (bias != nullptr) ? bias[col] : 0.0f;
            #pragma unroll
            for (int r = 0; r < 4; ++r) {
                const int row = m0 + wm + im * 16 + rowq + r;
                C[(size_t)row * N + col] = (acc[im][in_][r] + badd) * TANH_SCALE;
            }
        }
    }
}

// ---------------------------------------------------------------------------
// attn v4: NF=2 (reverted from NF=4 regression) + DEFERRED reduction.
// Phase-1 keeps per-lane partials s0[8]/s1[8] in registers (no shuffles in
// the hot loop); one LDS transpose-reduce afterwards. Critical path becomes
// transc-throughput-bound instead of shuffle-latency-bound.
// ---------------------------------------------------------------------------
__global__ __launch_bounds__(256, 4) void attn_fused(
    const float* __restrict__ feat,   // [B,F,D] raw
    const float* __restrict__ txt,    // [B,T,D] raw
    const int*   __restrict__ qmask,  // [B,T]
    const float* __restrict__ fp_s,   // [B*F,D]  feat_proj * c
    const float* __restrict__ tp_s,   // [B*T,D]  (txt_proj+b) * c
    const float* __restrict__ wvec,   // [D]
    const float* __restrict__ Wcw,    // [D]
    const float* __restrict__ bcw,    // [1]
    const float* __restrict__ Wcb,    // [D]
    const float* __restrict__ bcb,    // [1]
    float* __restrict__ out)          // [B,F,D]
{
    const int blk  = blockIdx.x;          // 0..1023
    const int f0   = blk * 2;
    const int b    = f0 >> 8;
    const int tid  = threadIdx.x;
    const int lane = tid & 63;
    const int wave = tid >> 6;

    // stride 68 pads banks: writes 2-way, b128 reads 2-way (free per m136)
    __shared__ float part[2][Tdim][68];   // 17.4 KB
    __shared__ float srho[2][Tdim];
    __shared__ float satt[2][Tdim];
    __shared__ float sred[4][4];

    float4 wv[4], fva[4], fvb[4];
    const float* fr0 = fp_s + (size_t)f0 * Ddim;
    const float* fr1 = fr0 + Ddim;
    #pragma unroll
    for (int it = 0; it < 4; ++it) {
        const int d = lane * 4 + it * 256;
        wv[it]  = *(const float4*)&wvec[d];
        fva[it] = *(const float4*)&fr0[d];
        fvb[it] = *(const float4*)&fr1[d];
    }
    float sumw = 0.0f;
    #pragma unroll
    for (int it = 0; it < 4; ++it)
        sumw += wv[it].x + wv[it].y + wv[it].z + wv[it].w;
    #pragma unroll
    for (int off = 32; off; off >>= 1) sumw += __shfl_xor(sumw, off, 64);

    // ---- phase 1: partial logits, NO cross-lane ops in the loop ----
    const float* tpb = tp_s + (size_t)b * Tdim * Ddim;
    float s0[8], s1[8];
    #pragma unroll
    for (int tt = 0; tt < 8; ++tt) {
        const int t = wave * 8 + tt;
        const float* tr = tpb + (size_t)t * Ddim;
        float a0 = 0.0f, b0 = 0.0f, a1 = 0.0f, b1 = 0.0f;
        #pragma unroll
        for (int it = 0; it < 4; ++it) {
            const int d = lane * 4 + it * 256;
            float4 tv = *(const float4*)&tr[d];
            float e, r;
            e = fexp2(tv.x + fva[it].x); r = frcp(e + 1.0f); a0 = fmaf(wv[it].x, r, a0);
            e = fexp2(tv.y + fva[it].y); r = frcp(e + 1.0f); b0 = fmaf(wv[it].y, r, b0);
            e = fexp2(tv.z + fva[it].z); r = frcp(e + 1.0f); a0 = fmaf(wv[it].z, r, a0);
            e = fexp2(tv.w + fva[it].w); r = frcp(e + 1.0f); b0 = fmaf(wv[it].w, r, b0);
            e = fexp2(tv.x + fvb[it].x); r = frcp(e + 1.0f); a1 = fmaf(wv[it].x, r, a1);
            e = fexp2(tv.y + fvb[it].y); r = frcp(e + 1.0f); b1 = fmaf(wv[it].y, r, b1);
            e = fexp2(tv.z + fvb[it].z); r = frcp(e + 1.0f); a1 = fmaf(wv[it].z, r, a1);
            e = fexp2(tv.w + fvb[it].w); r = frcp(e + 1.0f); b1 = fmaf(wv[it].w, r, b1);
        }
        s0[tt] = a0 + b0;
        s1[tt] = a1 + b1;
    }
    #pragma unroll
    for (int tt = 0; tt < 8; ++tt) {
        part[0][wave * 8 + tt][lane] = s0[tt];
        part[1][wave * 8 + tt][lane] = s1[tt];
    }
    __syncthreads();

    // ---- deferred reduction: 4 threads per (f,t) pair ----
    {
        const int pair = tid >> 2, q = tid & 3;   // pair threads are adjacent lanes
        const int f = pair >> 5, t = pair & 31;
        const float* src = &part[f][t][q * 16];
        float4 v0 = *(const float4*)(src);
        float4 v1 = *(const float4*)(src + 4);
        float4 v2 = *(const float4*)(src + 8);
        float4 v3 = *(const float4*)(src + 12);
        float sum = ((v0.x + v0.y) + (v0.z + v0.w))
                  + ((v1.x + v1.y) + (v1.z + v1.w))
                  + ((v2.x + v2.y) + (v2.z + v2.w))
                  + ((v3.x + v3.y) + (v3.z + v3.w));
        sum += __shfl_xor(sum, 1, 64);
        sum += __shfl_xor(sum, 2, 64);
        if (q == 0) srho[f][t] = sum;
    }
    __syncthreads();

    // ---- softmax: wave 0, 32 lanes per f-row ----
    if (wave == 0) {
        const int f = lane >> 5, t = lane & 31;
        const float q = (float)qmask[b * Tdim + t];
        float L = sumw - 2.0f * srho[f][t] + (1.0f - q) * NEGV;
        float m = L;
        #pragma unroll
        for (int off = 16; off; off >>= 1) m = fmaxf(m, __shfl_xor(m, off, 64));
        float e = fexp2((L - m) * LOG2E);
        float ssum = e;
        #pragma unroll
        for (int off = 16; off; off >>= 1) ssum += __shfl_xor(ssum, off, 64);
        satt[f][t] = e * frcp(ssum);
    }
    __syncthreads();

    // ---- phase 2: txt_h for both f rows; thread owns d0 = tid*4 ----
    const float* txtb = txt + (size_t)b * Tdim * Ddim;
    const int d0 = tid * 4;
    float4 th0 = {0,0,0,0}, th1 = {0,0,0,0};
    #pragma unroll 8
    for (int t = 0; t < Tdim; ++t) {
        float4 tv = *(const float4*)&txtb[(size_t)t * Ddim + d0];
        const float a0 = satt[0][t], a1 = satt[1][t];
        th0.x = fmaf(a0, tv.x, th0.x); th0.y = fmaf(a0, tv.y, th0.y);
        th0.z = fmaf(a0, tv.z, th0.z); th0.w = fmaf(a0, tv.w, th0.w);
        th1.x = fmaf(a1, tv.x, th1.x); th1.y = fmaf(a1, tv.y, th1.y);
        th1.z = fmaf(a1, tv.z, th1.z); th1.w = fmaf(a1, tv.w, th1.w);
    }

    float4 wcw = *(const float4*)&Wcw[d0];
    float4 wcb = *(const float4*)&Wcb[d0];
    float p00 = th0.x*wcw.x + th0.y*wcw.y + th0.z*wcw.z + th0.w*wcw.w;
    float p01 = th0.x*wcb.x + th0.y*wcb.y + th0.z*wcb.z + th0.w*wcb.w;
    float p10 = th1.x*wcw.x + th1.y*wcw.y + th1.z*wcw.z + th1.w*wcw.w;
    float p11 = th1.x*wcb.x + th1.y*wcb.y + th1.z*wcb.z + th1.w*wcb.w;
    #pragma unroll
    for (int off = 32; off; off >>= 1) {
        p00 += __shfl_xor(p00, off, 64);
        p01 += __shfl_xor(p01, off, 64);
        p10 += __shfl_xor(p10, off, 64);
        p11 += __shfl_xor(p11, off, 64);
    }
    if (lane == 0) {
        sred[wave][0] = p00; sred[wave][1] = p01;
        sred[wave][2] = p10; sred[wave][3] = p11;
    }
    __syncthreads();
    const float c00 = sred[0][0] + sred[1][0] + sred[2][0] + sred[3][0];
    const float c01 = sred[0][1] + sred[1][1] + sred[2][1] + sred[3][1];
    const float c10 = sred[0][2] + sred[1][2] + sred[2][2] + sred[3][2];
    const float c11 = sred[0][3] + sred[1][3] + sred[2][3] + sred[3][3];
    const float ws0 = fast_tanh(c00 + bcw[0]);
    const float bs0 = fast_tanh(c01 + bcb[0]);
    const float ws1 = fast_tanh(c10 + bcw[0]);
    const float bs1 = fast_tanh(c11 + bcb[0]);

    const float* ft0 = feat + (size_t)f0 * Ddim;
    float4 v0 = *(const float4*)&ft0[d0];
    float4 v1 = *(const float4*)&ft0[Ddim + d0];
    float4 o0, o1;
    o0.x = fmaf(ws0, v0.x, bs0); o0.y = fmaf(ws0, v0.y, bs0);
    o0.z = fmaf(ws0, v0.z, bs0); o0.w = fmaf(ws0, v0.w, bs0);
    o1.x = fmaf(ws1, v1.x, bs1); o1.y = fmaf(ws1, v1.y, bs1);
    o1.z = fmaf(ws1, v1.z, bs1); o1.w = fmaf(ws1, v1.w, bs1);
    *(float4*)&out[(size_t)f0 * Ddim + d0] = o0;
    *(float4*)&out[(size_t)f0 * Ddim + Ddim + d0] = o1;
}

// ---------------------------------------------------------------------------
extern "C" void kernel_launch(void* const* d_in, const int* in_sizes, int n_in,
                              void* d_out, int out_size, void* d_ws, size_t ws_size,
                              hipStream_t stream) {
    const float* features = (const float*)d_in[0];   // [B,F,D]
    const float* textual  = (const float*)d_in[2];   // [B,T,D]
    const int*   q_masks  = (const int*)d_in[3];     // [B,T]
    const float* Ws       = (const float*)d_in[4];   // [D,D]
    const float* W        = (const float*)d_in[5];   // [D,D]
    const float* wvec     = (const float*)d_in[6];   // [D,1]
    const float* bvec     = (const float*)d_in[7];   // [1,D]
    const float* Wcw      = (const float*)d_in[8];   // [1,D]
    const float* bcw      = (const float*)d_in[9];   // [1]
    const float* Wcb      = (const float*)d_in[10];  // [1,D]
    const float* bcb      = (const float*)d_in[11];  // [1]
    float* out = (float*)d_out;

    float*  fp_ws = (float*)d_ws;                          // 2048*1024 f32 (scaled)
    float*  tp_ws = fp_ws + (size_t)Bdim * Fdim * Ddim;    // 256*1024 f32 (scaled)
    ushort* featB = (ushort*)(tp_ws + (size_t)Bdim * Tdim * Ddim);
    ushort* txtB  = featB + (size_t)Bdim * Fdim * Ddim;
    ushort* WtB   = txtB + (size_t)Bdim * Tdim * Ddim;
    ushort* WstB  = WtB + (size_t)Ddim * Ddim;

    // 1. merged prep: cast activations + transpose/cast weights
    prep<<<Bdim * Fdim + Bdim * Tdim + 2048, 256, 0, stream>>>(
        features, textual, W, Ws, featB, txtB, WtB, WstB);
    // 2. both projections, one MFMA dispatch (m97-style staging)
    gemm_dual<<<dim3(Ddim / GBN, 18), 256, 0, stream>>>(
        featB, WtB, fp_ws, txtB, WstB, tp_ws, bvec);
    // 3. fused attention + conditioning (2 f-rows per block, deferred reduce)
    attn_fused<<<(Bdim * Fdim) / 2, 256, 0, stream>>>(
        features, textual, q_masks, fp_ws, tp_ws,
        wvec, Wcw, bcw, Wcb, bcb, out);
}

// Round 7
// 128.149 us; speedup vs baseline: 1.0451x; 1.0264x over previous
//
#include <hip/hip_runtime.h>
#include <math.h>

// Problem constants (SCDM_89318139888190)
#define Bdim 8
#define Fdim 256
#define Tdim 32
#define Ddim 1024
#define NEGV (-1e30f)
#define TANH_SCALE 2.8853900817779268f   // 2*log2(e): tanh(x)=1-2*rcp(exp2(c*x)+1)
#define LOG2E 1.4426950408889634f

typedef unsigned short ushort;
using short8  = __attribute__((ext_vector_type(8))) short;   // 8 bf16 in 4 VGPRs
using floatx4 = __attribute__((ext_vector_type(4))) float;   // MFMA accumulator

__device__ __forceinline__ float fexp2(float x) { return __builtin_amdgcn_exp2f(x); }
__device__ __forceinline__ float frcp(float x)  { return __builtin_amdgcn_rcpf(x); }

__device__ __forceinline__ float fast_tanh(float x) {
    return 1.0f - 2.0f * frcp(fexp2(x * TANH_SCALE) + 1.0f);
}

__device__ __forceinline__ ushort f2bf(float f) {
    unsigned u = __float_as_uint(f);
    unsigned r = u + 0x7FFFu + ((u >> 16) & 1u);
    return (ushort)(r >> 16);
}

// async global->LDS, 16B per lane; LDS dst = base + lane*16 (wave-uniform base)
#define GLOAD_LDS16(gp, lp) __builtin_amdgcn_global_load_lds(                   \
    (const __attribute__((address_space(1))) void*)(gp),                        \
    (__attribute__((address_space(3))) void*)(lp), 16, 0, 0)

// ---------------------------------------------------------------------------
// prep (merged): blocks [0,2304) cast feat/txt rows to bf16;
// blocks [2304, 2304+2048) transpose+cast W / Ws 32x32 tiles.
// ---------------------------------------------------------------------------
__global__ __launch_bounds__(256) void prep(
    const float* __restrict__ feat, const float* __restrict__ txt,
    const float* __restrict__ W, const float* __restrict__ Ws,
    ushort* __restrict__ featB, ushort* __restrict__ txtB,
    ushort* __restrict__ WtB, ushort* __restrict__ WstB)
{
    __shared__ ushort tile[32][33];
    const int blk = blockIdx.x;
    const int NCAST = Bdim * Fdim + Bdim * Tdim;   // 2304
    if (blk < NCAST) {
        const float* in; ushort* out; int base;
        if (blk < Bdim * Fdim) { in = feat; out = featB; base = blk * Ddim; }
        else { in = txt; out = txtB; base = (blk - Bdim * Fdim) * Ddim; }
        const int i = base + threadIdx.x * 4;
        float4 v = *(const float4*)(in + i);
        ushort4 o;
        o.x = f2bf(v.x); o.y = f2bf(v.y); o.z = f2bf(v.z); o.w = f2bf(v.w);
        *(ushort4*)(out + i) = o;
    } else {
        int t = blk - NCAST;                      // 0..2047
        const float* in = (t < 1024) ? W : Ws;
        ushort* out = (t < 1024) ? WtB : WstB;
        t &= 1023;
        const int bx = (t & 31) * 32;             // col (n) base
        const int by = (t >> 5) * 32;             // row (k) base
        const int tx = threadIdx.x & 31;
        const int tg = threadIdx.x >> 5;
        #pragma unroll
        for (int r = tg; r < 32; r += 8)
            tile[r][tx] = f2bf(in[(size_t)(by + r) * Ddim + bx + tx]);
        __syncthreads();
        #pragma unroll
        for (int r = tg; r < 32; r += 8)
            out[(size_t)(bx + r) * Ddim + by + tx] = tile[tx][r];
    }
}

// ---------------------------------------------------------------------------
// bf16 MFMA GEMM, m97-style staging: BM=128, BN=64, BK=32, 256 threads.
// global_load_lds width=16 staging; wave computes 64x32 (4x2 of 16x16x32).
// blockIdx.y 0..15 -> feat_proj; 16..17 -> txt_proj (+bias).
// Epilogue scales by TANH_SCALE (outputs feed the tanh argument in attn).
// ---------------------------------------------------------------------------
#define GBM 128
#define GBN 64
#define GBK 32

__global__ __launch_bounds__(256) void gemm_dual(
    const ushort* __restrict__ A1, const ushort* __restrict__ Bt1, float* __restrict__ C1,
    const ushort* __restrict__ A2, const ushort* __restrict__ Bt2, float* __restrict__ C2,
    const float* __restrict__ bias2)
{
    const int K = Ddim, N = Ddim;
    const int by = blockIdx.y;
    const ushort* A; const ushort* Bt; float* C; const float* bias; int m0;
    if (by < 16) { A = A1; Bt = Bt1; C = C1; bias = nullptr; m0 = by * GBM; }
    else         { A = A2; Bt = Bt2; C = C2; bias = bias2;  m0 = (by - 16) * GBM; }
    const int n0 = blockIdx.x * GBN;

    __shared__ __align__(16) ushort As[GBM * GBK];   // 8 KB
    __shared__ __align__(16) ushort Bs[GBN * GBK];   // 4 KB

    const int tid  = threadIdx.x;
    const int l    = tid & 63;
    const int wave = tid >> 6;

    const int crow = l >> 2;
    const int ccol = (l & 3) * 8;

    const int wm = (wave >> 1) * 64;
    const int wn = (wave & 1) * 32;

    floatx4 acc[4][2];
    #pragma unroll
    for (int i = 0; i < 4; ++i)
        #pragma unroll
        for (int j = 0; j < 2; ++j)
            acc[i][j] = (floatx4){0.0f, 0.0f, 0.0f, 0.0f};

    const int lm = l & 15;
    const int lk = (l >> 4) * 8;

    const ushort* aSrc0 = A  + (size_t)(m0 + wave * 16       + crow) * K + ccol;
    const ushort* aSrc1 = A  + (size_t)(m0 + (wave + 4) * 16 + crow) * K + ccol;
    const ushort* bSrc  = Bt + (size_t)(n0 + wave * 16       + crow) * K + ccol;
    ushort* aDst0 = &As[(wave * 16) * GBK];
    ushort* aDst1 = &As[((wave + 4) * 16) * GBK];
    ushort* bDst  = &Bs[(wave * 16) * GBK];

    for (int k0 = 0; k0 < K; k0 += GBK) {
        __syncthreads();
        GLOAD_LDS16(aSrc0 + k0, aDst0);
        GLOAD_LDS16(aSrc1 + k0, aDst1);
        GLOAD_LDS16(bSrc  + k0, bDst);
        __syncthreads();

        short8 af0 = *(const short8*)&As[(wm +  0 + lm) * GBK + lk];
        short8 af1 = *(const short8*)&As[(wm + 16 + lm) * GBK + lk];
        short8 af2 = *(const short8*)&As[(wm + 32 + lm) * GBK + lk];
        short8 af3 = *(const short8*)&As[(wm + 48 + lm) * GBK + lk];
        short8 bf0 = *(const short8*)&Bs[(wn +  0 + lm) * GBK + lk];
        short8 bf1 = *(const short8*)&Bs[(wn + 16 + lm) * GBK + lk];
        acc[0][0] = __builtin_amdgcn_mfma_f32_16x16x32_bf16(af0, bf0, acc[0][0], 0, 0, 0);
        acc[0][1] = __builtin_amdgcn_mfma_f32_16x16x32_bf16(af0, bf1, acc[0][1], 0, 0, 0);
        acc[1][0] = __builtin_amdgcn_mfma_f32_16x16x32_bf16(af1, bf0, acc[1][0], 0, 0, 0);
        acc[1][1] = __builtin_amdgcn_mfma_f32_16x16x32_bf16(af1, bf1, acc[1][1], 0, 0, 0);
        acc[2][0] = __builtin_amdgcn_mfma_f32_16x16x32_bf16(af2, bf0, acc[2][0], 0, 0, 0);
        acc[2][1] = __builtin_amdgcn_mfma_f32_16x16x32_bf16(af2, bf1, acc[2][1], 0, 0, 0);
        acc[3][0] = __builtin_amdgcn_mfma_f32_16x16x32_bf16(af3, bf0, acc[3][0], 0, 0, 0);
        acc[3][1] = __builtin_amdgcn_mfma_f32_16x16x32_bf16(af3, bf1, acc[3][1], 0, 0, 0);
    }

    const int rowq = (l >> 4) * 4;
    #pragma unroll
    for (int im = 0; im < 4; ++im) {
        #pragma unroll
        for (int in_ = 0; in_ < 2; ++in_) {
            const int col = n0 + wn + in_ * 16 + lm;
            float badd = (bias != nullptr) ? bias[col] : 0.0f;
            #pragma unroll
            for (int r = 0; r < 4; ++r) {
                const int row = m0 + wm + im * 16 + rowq + r;
                C[(size_t)row * N + col] = (acc[im][in_][r] + badd) * TANH_SCALE;
            }
        }
    }
}

// ---------------------------------------------------------------------------
// attn v5: NF=2, deferred reduction, EXPLICIT register double-buffer prefetch
// of tp rows across tt iterations (hide L2 latency under the transc compute).
// ---------------------------------------------------------------------------
__global__ __launch_bounds__(256, 4) void attn_fused(
    const float* __restrict__ feat,   // [B,F,D] raw
    const float* __restrict__ txt,    // [B,T,D] raw
    const int*   __restrict__ qmask,  // [B,T]
    const float* __restrict__ fp_s,   // [B*F,D]  feat_proj * c
    const float* __restrict__ tp_s,   // [B*T,D]  (txt_proj+b) * c
    const float* __restrict__ wvec,   // [D]
    const float* __restrict__ Wcw,    // [D]
    const float* __restrict__ bcw,    // [1]
    const float* __restrict__ Wcb,    // [D]
    const float* __restrict__ bcb,    // [1]
    float* __restrict__ out)          // [B,F,D]
{
    const int blk  = blockIdx.x;          // 0..1023
    const int f0   = blk * 2;
    const int b    = f0 >> 8;
    const int tid  = threadIdx.x;
    const int lane = tid & 63;
    const int wave = tid >> 6;

    // stride 68 pads banks: writes 2-way, b128 reads 2-way (free per m136)
    __shared__ float part[2][Tdim][68];   // 17.4 KB
    __shared__ float srho[2][Tdim];
    __shared__ float satt[2][Tdim];
    __shared__ float sred[4][4];

    float4 wv[4], fva[4], fvb[4];
    const float* fr0 = fp_s + (size_t)f0 * Ddim;
    const float* fr1 = fr0 + Ddim;
    #pragma unroll
    for (int it = 0; it < 4; ++it) {
        const int d = lane * 4 + it * 256;
        wv[it]  = *(const float4*)&wvec[d];
        fva[it] = *(const float4*)&fr0[d];
        fvb[it] = *(const float4*)&fr1[d];
    }
    float sumw = 0.0f;
    #pragma unroll
    for (int it = 0; it < 4; ++it)
        sumw += wv[it].x + wv[it].y + wv[it].z + wv[it].w;
    #pragma unroll
    for (int off = 32; off; off >>= 1) sumw += __shfl_xor(sumw, off, 64);

    // ---- phase 1: partial logits, register double-buffered tp loads ----
    const float* tpb = tp_s + (size_t)b * Tdim * Ddim;
    float s0[8], s1[8];
    float4 cur[4], nxt[4];
    {
        const float* tr = tpb + (size_t)(wave * 8) * Ddim;
        #pragma unroll
        for (int it = 0; it < 4; ++it)
            cur[it] = *(const float4*)&tr[lane * 4 + it * 256];
    }
    #pragma unroll
    for (int tt = 0; tt < 8; ++tt) {
        if (tt < 7) {   // issue next row's loads BEFORE computing this row
            const float* trn = tpb + (size_t)(wave * 8 + tt + 1) * Ddim;
            #pragma unroll
            for (int it = 0; it < 4; ++it)
                nxt[it] = *(const float4*)&trn[lane * 4 + it * 256];
        }
        float a0 = 0.0f, b0 = 0.0f, a1 = 0.0f, b1 = 0.0f;
        #pragma unroll
        for (int it = 0; it < 4; ++it) {
            float4 tv = cur[it];
            float e, r;
            e = fexp2(tv.x + fva[it].x); r = frcp(e + 1.0f); a0 = fmaf(wv[it].x, r, a0);
            e = fexp2(tv.y + fva[it].y); r = frcp(e + 1.0f); b0 = fmaf(wv[it].y, r, b0);
            e = fexp2(tv.z + fva[it].z); r = frcp(e + 1.0f); a0 = fmaf(wv[it].z, r, a0);
            e = fexp2(tv.w + fva[it].w); r = frcp(e + 1.0f); b0 = fmaf(wv[it].w, r, b0);
            e = fexp2(tv.x + fvb[it].x); r = frcp(e + 1.0f); a1 = fmaf(wv[it].x, r, a1);
            e = fexp2(tv.y + fvb[it].y); r = frcp(e + 1.0f); b1 = fmaf(wv[it].y, r, b1);
            e = fexp2(tv.z + fvb[it].z); r = frcp(e + 1.0f); a1 = fmaf(wv[it].z, r, a1);
            e = fexp2(tv.w + fvb[it].w); r = frcp(e + 1.0f); b1 = fmaf(wv[it].w, r, b1);
        }
        s0[tt] = a0 + b0;
        s1[tt] = a1 + b1;
        #pragma unroll
        for (int it = 0; it < 4; ++it) cur[it] = nxt[it];
    }
    #pragma unroll
    for (int tt = 0; tt < 8; ++tt) {
        part[0][wave * 8 + tt][lane] = s0[tt];
        part[1][wave * 8 + tt][lane] = s1[tt];
    }
    __syncthreads();

    // ---- deferred reduction: 4 threads per (f,t) pair ----
    {
        const int pair = tid >> 2, q = tid & 3;
        const int f = pair >> 5, t = pair & 31;
        const float* src = &part[f][t][q * 16];
        float4 v0 = *(const float4*)(src);
        float4 v1 = *(const float4*)(src + 4);
        float4 v2 = *(const float4*)(src + 8);
        float4 v3 = *(const float4*)(src + 12);
        float sum = ((v0.x + v0.y) + (v0.z + v0.w))
                  + ((v1.x + v1.y) + (v1.z + v1.w))
                  + ((v2.x + v2.y) + (v2.z + v2.w))
                  + ((v3.x + v3.y) + (v3.z + v3.w));
        sum += __shfl_xor(sum, 1, 64);
        sum += __shfl_xor(sum, 2, 64);
        if (q == 0) srho[f][t] = sum;
    }
    __syncthreads();

    // ---- softmax: wave 0, 32 lanes per f-row ----
    if (wave == 0) {
        const int f = lane >> 5, t = lane & 31;
        const float q = (float)qmask[b * Tdim + t];
        float L = sumw - 2.0f * srho[f][t] + (1.0f - q) * NEGV;
        float m = L;
        #pragma unroll
        for (int off = 16; off; off >>= 1) m = fmaxf(m, __shfl_xor(m, off, 64));
        float e = fexp2((L - m) * LOG2E);
        float ssum = e;
        #pragma unroll
        for (int off = 16; off; off >>= 1) ssum += __shfl_xor(ssum, off, 64);
        satt[f][t] = e * frcp(ssum);
    }
    __syncthreads();

    // ---- phase 2: txt_h for both f rows; thread owns d0 = tid*4 ----
    const float* txtb = txt + (size_t)b * Tdim * Ddim;
    const int d0 = tid * 4;
    float4 th0 = {0,0,0,0}, th1 = {0,0,0,0};
    #pragma unroll 8
    for (int t = 0; t < Tdim; ++t) {
        float4 tv = *(const float4*)&txtb[(size_t)t * Ddim + d0];
        const float a0 = satt[0][t], a1 = satt[1][t];
        th0.x = fmaf(a0, tv.x, th0.x); th0.y = fmaf(a0, tv.y, th0.y);
        th0.z = fmaf(a0, tv.z, th0.z); th0.w = fmaf(a0, tv.w, th0.w);
        th1.x = fmaf(a1, tv.x, th1.x); th1.y = fmaf(a1, tv.y, th1.y);
        th1.z = fmaf(a1, tv.z, th1.z); th1.w = fmaf(a1, tv.w, th1.w);
    }

    float4 wcw = *(const float4*)&Wcw[d0];
    float4 wcb = *(const float4*)&Wcb[d0];
    float p00 = th0.x*wcw.x + th0.y*wcw.y + th0.z*wcw.z + th0.w*wcw.w;
    float p01 = th0.x*wcb.x + th0.y*wcb.y + th0.z*wcb.z + th0.w*wcb.w;
    float p10 = th1.x*wcw.x + th1.y*wcw.y + th1.z*wcw.z + th1.w*wcw.w;
    float p11 = th1.x*wcb.x + th1.y*wcb.y + th1.z*wcb.z + th1.w*wcb.w;
    #pragma unroll
    for (int off = 32; off; off >>= 1) {
        p00 += __shfl_xor(p00, off, 64);
        p01 += __shfl_xor(p01, off, 64);
        p10 += __shfl_xor(p10, off, 64);
        p11 += __shfl_xor(p11, off, 64);
    }
    if (lane == 0) {
        sred[wave][0] = p00; sred[wave][1] = p01;
        sred[wave][2] = p10; sred[wave][3] = p11;
    }
    __syncthreads();
    const float c00 = sred[0][0] + sred[1][0] + sred[2][0] + sred[3][0];
    const float c01 = sred[0][1] + sred[1][1] + sred[2][1] + sred[3][1];
    const float c10 = sred[0][2] + sred[1][2] + sred[2][2] + sred[3][2];
    const float c11 = sred[0][3] + sred[1][3] + sred[2][3] + sred[3][3];
    const float ws0 = fast_tanh(c00 + bcw[0]);
    const float bs0 = fast_tanh(c01 + bcb[0]);
    const float ws1 = fast_tanh(c10 + bcw[0]);
    const float bs1 = fast_tanh(c11 + bcb[0]);

    const float* ft0 = feat + (size_t)f0 * Ddim;
    float4 v0 = *(const float4*)&ft0[d0];
    float4 v1 = *(const float4*)&ft0[Ddim + d0];
    float4 o0, o1;
    o0.x = fmaf(ws0, v0.x, bs0); o0.y = fmaf(ws0, v0.y, bs0);
    o0.z = fmaf(ws0, v0.z, bs0); o0.w = fmaf(ws0, v0.w, bs0);
    o1.x = fmaf(ws1, v1.x, bs1); o1.y = fmaf(ws1, v1.y, bs1);
    o1.z = fmaf(ws1, v1.z, bs1); o1.w = fmaf(ws1, v1.w, bs1);
    *(float4*)&out[(size_t)f0 * Ddim + d0] = o0;
    *(float4*)&out[(size_t)f0 * Ddim + Ddim + d0] = o1;
}

// ---------------------------------------------------------------------------
extern "C" void kernel_launch(void* const* d_in, const int* in_sizes, int n_in,
                              void* d_out, int out_size, void* d_ws, size_t ws_size,
                              hipStream_t stream) {
    const float* features = (const float*)d_in[0];   // [B,F,D]
    const float* textual  = (const float*)d_in[2];   // [B,T,D]
    const int*   q_masks  = (const int*)d_in[3];     // [B,T]
    const float* Ws       = (const float*)d_in[4];   // [D,D]
    const float* W        = (const float*)d_in[5];   // [D,D]
    const float* wvec     = (const float*)d_in[6];   // [D,1]
    const float* bvec     = (const float*)d_in[7];   // [1,D]
    const float* Wcw      = (const float*)d_in[8];   // [1,D]
    const float* bcw      = (const float*)d_in[9];   // [1]
    const float* Wcb      = (const float*)d_in[10];  // [1,D]
    const float* bcb      = (const float*)d_in[11];  // [1]
    float* out = (float*)d_out;

    float*  fp_ws = (float*)d_ws;                          // 2048*1024 f32 (scaled)
    float*  tp_ws = fp_ws + (size_t)Bdim * Fdim * Ddim;    // 256*1024 f32 (scaled)
    ushort* featB = (ushort*)(tp_ws + (size_t)Bdim * Tdim * Ddim);
    ushort* txtB  = featB + (size_t)Bdim * Fdim * Ddim;
    ushort* WtB   = txtB + (size_t)Bdim * Tdim * Ddim;
    ushort* WstB  = WtB + (size_t)Ddim * Ddim;

    // 1. merged prep: cast activations + transpose/cast weights
    prep<<<Bdim * Fdim + Bdim * Tdim + 2048, 256, 0, stream>>>(
        features, textual, W, Ws, featB, txtB, WtB, WstB);
    // 2. both projections, one MFMA dispatch (m97-style staging)
    gemm_dual<<<dim3(Ddim / GBN, 18), 256, 0, stream>>>(
        featB, WtB, fp_ws, txtB, WstB, tp_ws, bvec);
    // 3. fused attention + conditioning (2 f-rows/block, prefetch + deferred reduce)
    attn_fused<<<(Bdim * Fdim) / 2, 256, 0, stream>>>(
        features, textual, q_masks, fp_ws, tp_ws,
        wvec, Wcw, bcw, Wcb, bcb, out);
}

// Round 8
// 127.438 us; speedup vs baseline: 1.0510x; 1.0056x over previous
//
#include <hip/hip_runtime.h>
#include <math.h>

// Problem constants (SCDM_89318139888190)
#define Bdim 8
#define Fdim 256
#define Tdim 32
#define Ddim 1024
#define NEGV (-1e30f)
#define TANH_SCALE 2.8853900817779268f   // 2*log2(e): tanh(x)=1-2*rcp(exp2(c*x)+1)
#define LOG2E 1.4426950408889634f

typedef unsigned short ushort;
using short8  = __attribute__((ext_vector_type(8))) short;   // 8 bf16 in 4 VGPRs
using floatx4 = __attribute__((ext_vector_type(4))) float;   // MFMA accumulator

__device__ __forceinline__ float fexp2(float x) { return __builtin_amdgcn_exp2f(x); }
__device__ __forceinline__ float frcp(float x)  { return __builtin_amdgcn_rcpf(x); }

__device__ __forceinline__ float fast_tanh(float x) {
    return 1.0f - 2.0f * frcp(fexp2(x * TANH_SCALE) + 1.0f);
}

__device__ __forceinline__ ushort f2bf(float f) {
    unsigned u = __float_as_uint(f);
    unsigned r = u + 0x7FFFu + ((u >> 16) & 1u);
    return (ushort)(r >> 16);
}

// async global->LDS, 16B per lane; LDS dst = base + lane*16 (wave-uniform base)
#define GLOAD_LDS16(gp, lp) __builtin_amdgcn_global_load_lds(                   \
    (const __attribute__((address_space(1))) void*)(gp),                        \
    (__attribute__((address_space(3))) void*)(lp), 16, 0, 0)

// gfx9 s_waitcnt immediate: vmcnt[3:0]=bits3:0, expcnt=bits6:4, lgkmcnt=bits11:8,
// vmcnt[5:4]=bits15:14. Leave expcnt/lgkmcnt unconstrained (max).
#define WAIT_VMCNT(n) __builtin_amdgcn_s_waitcnt(((n) & 0xF) | (7 << 4) | (15 << 8) | (((n) >> 4) << 14))

// ---------------------------------------------------------------------------
// prep (merged): blocks [0,2304) cast feat/txt rows to bf16;
// blocks [2304, 2304+2048) transpose+cast W / Ws 32x32 tiles.
// ---------------------------------------------------------------------------
__global__ __launch_bounds__(256) void prep(
    const float* __restrict__ feat, const float* __restrict__ txt,
    const float* __restrict__ W, const float* __restrict__ Ws,
    ushort* __restrict__ featB, ushort* __restrict__ txtB,
    ushort* __restrict__ WtB, ushort* __restrict__ WstB)
{
    __shared__ ushort tile[32][33];
    const int blk = blockIdx.x;
    const int NCAST = Bdim * Fdim + Bdim * Tdim;   // 2304
    if (blk < NCAST) {
        const float* in; ushort* out; int base;
        if (blk < Bdim * Fdim) { in = feat; out = featB; base = blk * Ddim; }
        else { in = txt; out = txtB; base = (blk - Bdim * Fdim) * Ddim; }
        const int i = base + threadIdx.x * 4;
        float4 v = *(const float4*)(in + i);
        ushort4 o;
        o.x = f2bf(v.x); o.y = f2bf(v.y); o.z = f2bf(v.z); o.w = f2bf(v.w);
        *(ushort4*)(out + i) = o;
    } else {
        int t = blk - NCAST;                      // 0..2047
        const float* in = (t < 1024) ? W : Ws;
        ushort* out = (t < 1024) ? WtB : WstB;
        t &= 1023;
        const int bx = (t & 31) * 32;             // col (n) base
        const int by = (t >> 5) * 32;             // row (k) base
        const int tx = threadIdx.x & 31;
        const int tg = threadIdx.x >> 5;
        #pragma unroll
        for (int r = tg; r < 32; r += 8)
            tile[r][tx] = f2bf(in[(size_t)(by + r) * Ddim + bx + tx]);
        __syncthreads();
        #pragma unroll
        for (int r = tg; r < 32; r += 8)
            out[(size_t)(bx + r) * Ddim + by + tx] = tile[tx][r];
    }
}

// ---------------------------------------------------------------------------
// bf16 MFMA GEMM v3: BM=128, BN=64, BK=32, 256 threads, EXPLICIT LDS
// double-buffer with raw s_barrier + manual vmcnt — prefetch loads stay in
// flight across the barrier (no vmcnt(0) drain). Needed because grid=288
// gives ~1 block/CU: no other resident waves to hide the drain (m114-style
// implicit overlap unavailable).
//   iter i: prefetch tile i+1 -> buf[(i+1)&1]; wait vmcnt(3) (tile i done);
//           s_barrier; ds_read+MFMA from buf[i&1]; s_barrier (readers done
//           before anyone prefetches into this buffer next iter).
// ---------------------------------------------------------------------------
#define GBM 128
#define GBN 64
#define GBK 32

__global__ __launch_bounds__(256) void gemm_dual(
    const ushort* __restrict__ A1, const ushort* __restrict__ Bt1, float* __restrict__ C1,
    const ushort* __restrict__ A2, const ushort* __restrict__ Bt2, float* __restrict__ C2,
    const float* __restrict__ bias2)
{
    const int K = Ddim, N = Ddim;
    const int by = blockIdx.y;
    const ushort* A; const ushort* Bt; float* C; const float* bias; int m0;
    if (by < 16) { A = A1; Bt = Bt1; C = C1; bias = nullptr; m0 = by * GBM; }
    else         { A = A2; Bt = Bt2; C = C2; bias = bias2;  m0 = (by - 16) * GBM; }
    const int n0 = blockIdx.x * GBN;

    __shared__ __align__(16) ushort As[2][GBM * GBK];   // 2 x 8 KB
    __shared__ __align__(16) ushort Bs[2][GBN * GBK];   // 2 x 4 KB

    const int tid  = threadIdx.x;
    const int l    = tid & 63;
    const int wave = tid >> 6;

    const int wm = (wave >> 1) * 64;
    const int wn = (wave & 1) * 32;

    floatx4 acc[4][2];
    #pragma unroll
    for (int i = 0; i < 4; ++i)
        #pragma unroll
        for (int j = 0; j < 2; ++j)
            acc[i][j] = (floatx4){0.0f, 0.0f, 0.0f, 0.0f};

    const int lm = l & 15;
    const int lk = (l >> 4) * 8;

    const int crow = l >> 2;          // staging row within 16-row chunk
    const int ccol = (l & 3) * 8;     // staging k (ushort)

    const ushort* aSrc0 = A  + (size_t)(m0 + wave * 16       + crow) * K + ccol;
    const ushort* aSrc1 = A  + (size_t)(m0 + (wave + 4) * 16 + crow) * K + ccol;
    const ushort* bSrc  = Bt + (size_t)(n0 + wave * 16       + crow) * K + ccol;
    const int aOff0 = (wave * 16) * GBK;        // + lane*16B implicit in gload_lds
    const int aOff1 = ((wave + 4) * 16) * GBK;
    const int bOff  = (wave * 16) * GBK;

    const int NK = K / GBK;   // 32

    // prologue: tile 0 -> buf 0
    GLOAD_LDS16(aSrc0, &As[0][aOff0]);
    GLOAD_LDS16(aSrc1, &As[0][aOff1]);
    GLOAD_LDS16(bSrc,  &Bs[0][bOff]);

    for (int i = 0; i < NK; ++i) {
        const int cur = i & 1;
        if (i + 1 < NK) {
            const int kn = (i + 1) * GBK;
            const int nxt = cur ^ 1;
            GLOAD_LDS16(aSrc0 + kn, &As[nxt][aOff0]);
            GLOAD_LDS16(aSrc1 + kn, &As[nxt][aOff1]);
            GLOAD_LDS16(bSrc  + kn, &Bs[nxt][bOff]);
            WAIT_VMCNT(3);     // tile i's 3 loads retired; tile i+1 in flight
        } else {
            WAIT_VMCNT(0);
        }
        __builtin_amdgcn_s_barrier();   // tile i visible to all waves

        short8 af0 = *(const short8*)&As[cur][(wm +  0 + lm) * GBK + lk];
        short8 af1 = *(const short8*)&As[cur][(wm + 16 + lm) * GBK + lk];
        short8 af2 = *(const short8*)&As[cur][(wm + 32 + lm) * GBK + lk];
        short8 af3 = *(const short8*)&As[cur][(wm + 48 + lm) * GBK + lk];
        short8 bf0 = *(const short8*)&Bs[cur][(wn +  0 + lm) * GBK + lk];
        short8 bf1 = *(const short8*)&Bs[cur][(wn + 16 + lm) * GBK + lk];
        acc[0][0] = __builtin_amdgcn_mfma_f32_16x16x32_bf16(af0, bf0, acc[0][0], 0, 0, 0);
        acc[0][1] = __builtin_amdgcn_mfma_f32_16x16x32_bf16(af0, bf1, acc[0][1], 0, 0, 0);
        acc[1][0] = __builtin_amdgcn_mfma_f32_16x16x32_bf16(af1, bf0, acc[1][0], 0, 0, 0);
        acc[1][1] = __builtin_amdgcn_mfma_f32_16x16x32_bf16(af1, bf1, acc[1][1], 0, 0, 0);
        acc[2][0] = __builtin_amdgcn_mfma_f32_16x16x32_bf16(af2, bf0, acc[2][0], 0, 0, 0);
        acc[2][1] = __builtin_amdgcn_mfma_f32_16x16x32_bf16(af2, bf1, acc[2][1], 0, 0, 0);
        acc[3][0] = __builtin_amdgcn_mfma_f32_16x16x32_bf16(af3, bf0, acc[3][0], 0, 0, 0);
        acc[3][1] = __builtin_amdgcn_mfma_f32_16x16x32_bf16(af3, bf1, acc[3][1], 0, 0, 0);

        __builtin_amdgcn_s_barrier();   // all readers of buf[cur] done
    }

    const int rowq = (l >> 4) * 4;
    #pragma unroll
    for (int im = 0; im < 4; ++im) {
        #pragma unroll
        for (int in_ = 0; in_ < 2; ++in_) {
            const int col = n0 + wn + in_ * 16 + lm;
            float badd = (bias != nullptr) ? bias[col] : 0.0f;
            #pragma unroll
            for (int r = 0; r < 4; ++r) {
                const int row = m0 + wm + im * 16 + rowq + r;
                C[(size_t)row * N + col] = (acc[im][in_][r] + badd) * TANH_SCALE;
            }
        }
    }
}

// ---------------------------------------------------------------------------
// attn v5 (frozen): NF=2, deferred reduction, register double-buffer prefetch.
// ---------------------------------------------------------------------------
__global__ __launch_bounds__(256, 4) void attn_fused(
    const float* __restrict__ feat,   // [B,F,D] raw
    const float* __restrict__ txt,    // [B,T,D] raw
    const int*   __restrict__ qmask,  // [B,T]
    const float* __restrict__ fp_s,   // [B*F,D]  feat_proj * c
    const float* __restrict__ tp_s,   // [B*T,D]  (txt_proj+b) * c
    const float* __restrict__ wvec,   // [D]
    const float* __restrict__ Wcw,    // [D]
    const float* __restrict__ bcw,    // [1]
    const float* __restrict__ Wcb,    // [D]
    const float* __restrict__ bcb,    // [1]
    float* __restrict__ out)          // [B,F,D]
{
    const int blk  = blockIdx.x;          // 0..1023
    const int f0   = blk * 2;
    const int b    = f0 >> 8;
    const int tid  = threadIdx.x;
    const int lane = tid & 63;
    const int wave = tid >> 6;

    __shared__ float part[2][Tdim][68];   // stride 68: 2-way banks (free)
    __shared__ float srho[2][Tdim];
    __shared__ float satt[2][Tdim];
    __shared__ float sred[4][4];

    float4 wv[4], fva[4], fvb[4];
    const float* fr0 = fp_s + (size_t)f0 * Ddim;
    const float* fr1 = fr0 + Ddim;
    #pragma unroll
    for (int it = 0; it < 4; ++it) {
        const int d = lane * 4 + it * 256;
        wv[it]  = *(const float4*)&wvec[d];
        fva[it] = *(const float4*)&fr0[d];
        fvb[it] = *(const float4*)&fr1[d];
    }
    float sumw = 0.0f;
    #pragma unroll
    for (int it = 0; it < 4; ++it)
        sumw += wv[it].x + wv[it].y + wv[it].z + wv[it].w;
    #pragma unroll
    for (int off = 32; off; off >>= 1) sumw += __shfl_xor(sumw, off, 64);

    // ---- phase 1: partial logits, register double-buffered tp loads ----
    const float* tpb = tp_s + (size_t)b * Tdim * Ddim;
    float s0[8], s1[8];
    float4 cur[4], nxt[4];
    {
        const float* tr = tpb + (size_t)(wave * 8) * Ddim;
        #pragma unroll
        for (int it = 0; it < 4; ++it)
            cur[it] = *(const float4*)&tr[lane * 4 + it * 256];
    }
    #pragma unroll
    for (int tt = 0; tt < 8; ++tt) {
        if (tt < 7) {
            const float* trn = tpb + (size_t)(wave * 8 + tt + 1) * Ddim;
            #pragma unroll
            for (int it = 0; it < 4; ++it)
                nxt[it] = *(const float4*)&trn[lane * 4 + it * 256];
        }
        float a0 = 0.0f, b0 = 0.0f, a1 = 0.0f, b1 = 0.0f;
        #pragma unroll
        for (int it = 0; it < 4; ++it) {
            float4 tv = cur[it];
            float e, r;
            e = fexp2(tv.x + fva[it].x); r = frcp(e + 1.0f); a0 = fmaf(wv[it].x, r, a0);
            e = fexp2(tv.y + fva[it].y); r = frcp(e + 1.0f); b0 = fmaf(wv[it].y, r, b0);
            e = fexp2(tv.z + fva[it].z); r = frcp(e + 1.0f); a0 = fmaf(wv[it].z, r, a0);
            e = fexp2(tv.w + fva[it].w); r = frcp(e + 1.0f); b0 = fmaf(wv[it].w, r, b0);
            e = fexp2(tv.x + fvb[it].x); r = frcp(e + 1.0f); a1 = fmaf(wv[it].x, r, a1);
            e = fexp2(tv.y + fvb[it].y); r = frcp(e + 1.0f); b1 = fmaf(wv[it].y, r, b1);
            e = fexp2(tv.z + fvb[it].z); r = frcp(e + 1.0f); a1 = fmaf(wv[it].z, r, a1);
            e = fexp2(tv.w + fvb[it].w); r = frcp(e + 1.0f); b1 = fmaf(wv[it].w, r, b1);
        }
        s0[tt] = a0 + b0;
        s1[tt] = a1 + b1;
        #pragma unroll
        for (int it = 0; it < 4; ++it) cur[it] = nxt[it];
    }
    #pragma unroll
    for (int tt = 0; tt < 8; ++tt) {
        part[0][wave * 8 + tt][lane] = s0[tt];
        part[1][wave * 8 + tt][lane] = s1[tt];
    }
    __syncthreads();

    // ---- deferred reduction: 4 threads per (f,t) pair ----
    {
        const int pair = tid >> 2, q = tid & 3;
        const int f = pair >> 5, t = pair & 31;
        const float* src = &part[f][t][q * 16];
        float4 v0 = *(const float4*)(src);
        float4 v1 = *(const float4*)(src + 4);
        float4 v2 = *(const float4*)(src + 8);
        float4 v3 = *(const float4*)(src + 12);
        float sum = ((v0.x + v0.y) + (v0.z + v0.w))
                  + ((v1.x + v1.y) + (v1.z + v1.w))
                  + ((v2.x + v2.y) + (v2.z + v2.w))
                  + ((v3.x + v3.y) + (v3.z + v3.w));
        sum += __shfl_xor(sum, 1, 64);
        sum += __shfl_xor(sum, 2, 64);
        if (q == 0) srho[f][t] = sum;
    }
    __syncthreads();

    // ---- softmax: wave 0, 32 lanes per f-row ----
    if (wave == 0) {
        const int f = lane >> 5, t = lane & 31;
        const float q = (float)qmask[b * Tdim + t];
        float L = sumw - 2.0f * srho[f][t] + (1.0f - q) * NEGV;
        float m = L;
        #pragma unroll
        for (int off = 16; off; off >>= 1) m = fmaxf(m, __shfl_xor(m, off, 64));
        float e = fexp2((L - m) * LOG2E);
        float ssum = e;
        #pragma unroll
        for (int off = 16; off; off >>= 1) ssum += __shfl_xor(ssum, off, 64);
        satt[f][t] = e * frcp(ssum);
    }
    __syncthreads();

    // ---- phase 2: txt_h for both f rows; thread owns d0 = tid*4 ----
    const float* txtb = txt + (size_t)b * Tdim * Ddim;
    const int d0 = tid * 4;
    float4 th0 = {0,0,0,0}, th1 = {0,0,0,0};
    #pragma unroll 8
    for (int t = 0; t < Tdim; ++t) {
        float4 tv = *(const float4*)&txtb[(size_t)t * Ddim + d0];
        const float a0 = satt[0][t], a1 = satt[1][t];
        th0.x = fmaf(a0, tv.x, th0.x); th0.y = fmaf(a0, tv.y, th0.y);
        th0.z = fmaf(a0, tv.z, th0.z); th0.w = fmaf(a0, tv.w, th0.w);
        th1.x = fmaf(a1, tv.x, th1.x); th1.y = fmaf(a1, tv.y, th1.y);
        th1.z = fmaf(a1, tv.z, th1.z); th1.w = fmaf(a1, tv.w, th1.w);
    }

    float4 wcw = *(const float4*)&Wcw[d0];
    float4 wcb = *(const float4*)&Wcb[d0];
    float p00 = th0.x*wcw.x + th0.y*wcw.y + th0.z*wcw.z + th0.w*wcw.w;
    float p01 = th0.x*wcb.x + th0.y*wcb.y + th0.z*wcb.z + th0.w*wcb.w;
    float p10 = th1.x*wcw.x + th1.y*wcw.y + th1.z*wcw.z + th1.w*wcw.w;
    float p11 = th1.x*wcb.x + th1.y*wcb.y + th1.z*wcb.z + th1.w*wcb.w;
    #pragma unroll
    for (int off = 32; off; off >>= 1) {
        p00 += __shfl_xor(p00, off, 64);
        p01 += __shfl_xor(p01, off, 64);
        p10 += __shfl_xor(p10, off, 64);
        p11 += __shfl_xor(p11, off, 64);
    }
    if (lane == 0) {
        sred[wave][0] = p00; sred[wave][1] = p01;
        sred[wave][2] = p10; sred[wave][3] = p11;
    }
    __syncthreads();
    const float c00 = sred[0][0] + sred[1][0] + sred[2][0] + sred[3][0];
    const float c01 = sred[0][1] + sred[1][1] + sred[2][1] + sred[3][1];
    const float c10 = sred[0][2] + sred[1][2] + sred[2][2] + sred[3][2];
    const float c11 = sred[0][3] + sred[1][3] + sred[2][3] + sred[3][3];
    const float ws0 = fast_tanh(c00 + bcw[0]);
    const float bs0 = fast_tanh(c01 + bcb[0]);
    const float ws1 = fast_tanh(c10 + bcw[0]);
    const float bs1 = fast_tanh(c11 + bcb[0]);

    const float* ft0 = feat + (size_t)f0 * Ddim;
    float4 v0 = *(const float4*)&ft0[d0];
    float4 v1 = *(const float4*)&ft0[Ddim + d0];
    float4 o0, o1;
    o0.x = fmaf(ws0, v0.x, bs0); o0.y = fmaf(ws0, v0.y, bs0);
    o0.z = fmaf(ws0, v0.z, bs0); o0.w = fmaf(ws0, v0.w, bs0);
    o1.x = fmaf(ws1, v1.x, bs1); o1.y = fmaf(ws1, v1.y, bs1);
    o1.z = fmaf(ws1, v1.z, bs1); o1.w = fmaf(ws1, v1.w, bs1);
    *(float4*)&out[(size_t)f0 * Ddim + d0] = o0;
    *(float4*)&out[(size_t)f0 * Ddim + Ddim + d0] = o1;
}

// ---------------------------------------------------------------------------
extern "C" void kernel_launch(void* const* d_in, const int* in_sizes, int n_in,
                              void* d_out, int out_size, void* d_ws, size_t ws_size,
                              hipStream_t stream) {
    const float* features = (const float*)d_in[0];   // [B,F,D]
    const float* textual  = (const float*)d_in[2];   // [B,T,D]
    const int*   q_masks  = (const int*)d_in[3];     // [B,T]
    const float* Ws       = (const float*)d_in[4];   // [D,D]
    const float* W        = (const float*)d_in[5];   // [D,D]
    const float* wvec     = (const float*)d_in[6];   // [D,1]
    const float* bvec     = (const float*)d_in[7];   // [1,D]
    const float* Wcw      = (const float*)d_in[8];   // [1,D]
    const float* bcw      = (const float*)d_in[9];   // [1]
    const float* Wcb      = (const float*)d_in[10];  // [1,D]
    const float* bcb      = (const float*)d_in[11];  // [1]
    float* out = (float*)d_out;

    float*  fp_ws = (float*)d_ws;                          // 2048*1024 f32 (scaled)
    float*  tp_ws = fp_ws + (size_t)Bdim * Fdim * Ddim;    // 256*1024 f32 (scaled)
    ushort* featB = (ushort*)(tp_ws + (size_t)Bdim * Tdim * Ddim);
    ushort* txtB  = featB + (size_t)Bdim * Fdim * Ddim;
    ushort* WtB   = txtB + (size_t)Bdim * Tdim * Ddim;
    ushort* WstB  = WtB + (size_t)Ddim * Ddim;

    // 1. merged prep: cast activations + transpose/cast weights
    prep<<<Bdim * Fdim + Bdim * Tdim + 2048, 256, 0, stream>>>(
        features, textual, W, Ws, featB, txtB, WtB, WstB);
    // 2. both projections, one MFMA dispatch (explicit dbuf, raw barriers)
    gemm_dual<<<dim3(Ddim / GBN, 18), 256, 0, stream>>>(
        featB, WtB, fp_ws, txtB, WstB, tp_ws, bvec);
    // 3. fused attention + conditioning (frozen)
    attn_fused<<<(Bdim * Fdim) / 2, 256, 0, stream>>>(
        features, textual, q_masks, fp_ws, tp_ws,
        wvec, Wcw, bcw, Wcb, bcb, out);
}